// Round 1
// baseline (4092.594 us; speedup 1.0000x reference)
//
#include <hip/hip_runtime.h>
#include <math.h>

#define HW_ 17424
#define WID 132
#define HGT 132
#define CH 256
#define MROWS 139392          // 8*17424
#define OUTOFF 35684352       // 8*256*17424

typedef __bf16 bf16x8 __attribute__((ext_vector_type(8)));
typedef float  f32x4  __attribute__((ext_vector_type(4)));

// Split 8 fp32 into hi/lo bf16 (RNE; residual is exact in fp32).
__device__ __forceinline__ void split8(const float* v, bf16x8& hi, bf16x8& lo) {
#pragma unroll
    for (int e = 0; e < 8; ++e) {
        float f = v[e];
        __bf16 h = (__bf16)f;
        hi[e] = h;
        lo[e] = (__bf16)(f - (float)h);
    }
}

// ---------------------------------------------------------------------------
// LayerNorm over channels with BCHW -> (M,256) transpose.  (unchanged, verified)
// ---------------------------------------------------------------------------
__global__ __launch_bounds__(256)
void ln_k(const float* __restrict__ x, const float* __restrict__ w,
          const float* __restrict__ bias, float* __restrict__ out) {
    __shared__ float4 s1[256];
    __shared__ float4 s2[256];
    const int tid = threadIdx.x;              // channel
    const int b   = blockIdx.y;
    const int hw0 = blockIdx.x << 2;          // 4 positions
    const float* px = x + ((size_t)(b * CH + tid)) * HW_ + hw0;
    float4 v = *(const float4*)px;
    s1[tid] = v;
    s2[tid] = make_float4(v.x * v.x, v.y * v.y, v.z * v.z, v.w * v.w);
    __syncthreads();
    for (int off = 128; off > 0; off >>= 1) {
        if (tid < off) {
            float4 a = s1[tid], c = s1[tid + off];
            a.x += c.x; a.y += c.y; a.z += c.z; a.w += c.w;
            s1[tid] = a;
            float4 d = s2[tid], e = s2[tid + off];
            d.x += e.x; d.y += e.y; d.z += e.z; d.w += e.w;
            s2[tid] = d;
        }
        __syncthreads();
    }
    float4 sum = s1[0], sq = s2[0];
    const float wv = w[tid], bv = bias[tid];
    const float inv = 1.0f / 256.0f;
    float o[4];
    {
        float m = sum.x * inv; float var = sq.x * inv - m * m;
        o[0] = (v.x - m) * rsqrtf(var + 1e-6f) * wv + bv;
    }
    {
        float m = sum.y * inv; float var = sq.y * inv - m * m;
        o[1] = (v.y - m) * rsqrtf(var + 1e-6f) * wv + bv;
    }
    {
        float m = sum.z * inv; float var = sq.z * inv - m * m;
        o[2] = (v.z - m) * rsqrtf(var + 1e-6f) * wv + bv;
    }
    {
        float m = sum.w * inv; float var = sq.w * inv - m * m;
        o[3] = (v.w - m) * rsqrtf(var + 1e-6f) * wv + bv;
    }
    float* po = out + ((size_t)(b * HW_ + hw0)) * CH + tid;
    po[0] = o[0]; po[256] = o[1]; po[512] = o[2]; po[768] = o[3];
}

// ---------------------------------------------------------------------------
// bf16x3 split-precision MFMA GEMM: C[M,N] = epi(A[M,K] @ W[K,N] + bias).
// 256 thr = 4 waves (2x2), block tile 128x128, wave tile 64x64 = 4x4 frags
// of v_mfma_f32_16x16x32_bf16.  A-frag: row = lane&15, k = (lane>>4)*8+e
// (contiguous 8).  B-frag: col = lane&15, same k slots.  D: col = lane&15,
// row = (lane>>4)*4 + reg  [measured: learn_hip m89].
// 3 MFMAs/tile: hi*hi + hi*lo + lo*hi  (rel err ~2^-16).
// EPI: 0 none, 1 exact GELU, 2 multiply by mulbuf elementwise.
// ---------------------------------------------------------------------------
template <int EPI, int KK, int NN>
__global__ __launch_bounds__(256, 2)
void mgemm_k(const float* __restrict__ A, const float* __restrict__ W,
             const float* __restrict__ bias, float* __restrict__ C,
             const float* __restrict__ mulbuf) {
    const int tid  = threadIdx.x;
    const int lane = tid & 63;
    const int wave = tid >> 6;
    const int wm = wave >> 1, wn = wave & 1;
    const int row0 = blockIdx.y * 128 + wm * 64;
    const int col0 = blockIdx.x * 128 + wn * 64;
    const int lrow = lane & 15;
    const int kg   = lane >> 4;

    const f32x4 zero = {0.f, 0.f, 0.f, 0.f};
    f32x4 acc[4][4];
#pragma unroll
    for (int i = 0; i < 4; ++i)
#pragma unroll
        for (int j = 0; j < 4; ++j) acc[i][j] = zero;

    for (int kt = 0; kt < KK; kt += 32) {
        const int kb = kt + kg * 8;
        bf16x8 ah[4], al[4], bh[4], bl[4];
#pragma unroll
        for (int mf = 0; mf < 4; ++mf) {
            const float* p = A + (size_t)(row0 + mf * 16 + lrow) * KK + kb;
            float buf[8];
            *(float4*)&buf[0] = *(const float4*)p;
            *(float4*)&buf[4] = *(const float4*)(p + 4);
            split8(buf, ah[mf], al[mf]);
        }
#pragma unroll
        for (int nf = 0; nf < 4; ++nf) {
            const float* p = W + (size_t)kb * NN + col0 + nf * 16 + lrow;
            float buf[8];
#pragma unroll
            for (int e = 0; e < 8; ++e) buf[e] = p[(size_t)e * NN];
            split8(buf, bh[nf], bl[nf]);
        }
#pragma unroll
        for (int mf = 0; mf < 4; ++mf)
#pragma unroll
            for (int nf = 0; nf < 4; ++nf) {
                f32x4 c = acc[mf][nf];
                c = __builtin_amdgcn_mfma_f32_16x16x32_bf16(al[mf], bh[nf], c, 0, 0, 0);
                c = __builtin_amdgcn_mfma_f32_16x16x32_bf16(ah[mf], bl[nf], c, 0, 0, 0);
                c = __builtin_amdgcn_mfma_f32_16x16x32_bf16(ah[mf], bh[nf], c, 0, 0, 0);
                acc[mf][nf] = c;
            }
    }

    float bv[4];
#pragma unroll
    for (int nf = 0; nf < 4; ++nf) bv[nf] = bias[col0 + nf * 16 + lrow];
#pragma unroll
    for (int mf = 0; mf < 4; ++mf) {
#pragma unroll
        for (int r = 0; r < 4; ++r) {
            const int row = row0 + mf * 16 + kg * 4 + r;
#pragma unroll
            for (int nf = 0; nf < 4; ++nf) {
                const int col = col0 + nf * 16 + lrow;
                const size_t off = (size_t)row * NN + col;
                float v = acc[mf][nf][r] + bv[nf];
                if (EPI == 1) v = 0.5f * v * (1.0f + erff(v * 0.7071067811865475f));
                if (EPI == 2) v *= mulbuf[off];
                C[off] = v;
            }
        }
    }
}

// ---------------------------------------------------------------------------
// Final projection, bf16x3 MFMA: cat = [g | l1 | l2] (each M x 128), K = 384,
// N = 512 = [proj | proje], output transposed to BCHW (out, out_e @ OUTOFF).
// ---------------------------------------------------------------------------
__global__ __launch_bounds__(256, 2)
void mgemm_proj_k(const float* __restrict__ g, const float* __restrict__ l1,
                  const float* __restrict__ l2,
                  const float* __restrict__ w1, const float* __restrict__ b1,
                  const float* __restrict__ w2, const float* __restrict__ b2,
                  float* __restrict__ out) {
    const int tid  = threadIdx.x;
    const int lane = tid & 63;
    const int wave = tid >> 6;
    const int wm = wave >> 1, wn = wave & 1;
    const int row0  = blockIdx.y * 128 + wm * 64;
    const int half  = blockIdx.x >> 1;              // 0 -> proj, 1 -> proje
    const int ncol0 = (blockIdx.x & 1) * 128 + wn * 64;
    const float* Wsel = half ? w2 : w1;
    const float* bsel = half ? b2 : b1;
    float* obase = out + (half ? (size_t)OUTOFF : (size_t)0);
    const int lrow = lane & 15;
    const int kg   = lane >> 4;

    const f32x4 zero = {0.f, 0.f, 0.f, 0.f};
    f32x4 acc[4][4];
#pragma unroll
    for (int i = 0; i < 4; ++i)
#pragma unroll
        for (int j = 0; j < 4; ++j) acc[i][j] = zero;

    for (int kt = 0; kt < 384; kt += 32) {
        const float* Ab = (kt < 128) ? g : (kt < 256) ? l1 : l2;
        const int kloc = (kt & 127) + kg * 8;
        bf16x8 ah[4], al[4], bh[4], bl[4];
#pragma unroll
        for (int mf = 0; mf < 4; ++mf) {
            const float* p = Ab + (size_t)(row0 + mf * 16 + lrow) * 128 + kloc;
            float buf[8];
            *(float4*)&buf[0] = *(const float4*)p;
            *(float4*)&buf[4] = *(const float4*)(p + 4);
            split8(buf, ah[mf], al[mf]);
        }
#pragma unroll
        for (int nf = 0; nf < 4; ++nf) {
            const float* p = Wsel + (size_t)(kt + kg * 8) * 256 + ncol0 + nf * 16 + lrow;
            float buf[8];
#pragma unroll
            for (int e = 0; e < 8; ++e) buf[e] = p[(size_t)e * 256];
            split8(buf, bh[nf], bl[nf]);
        }
#pragma unroll
        for (int mf = 0; mf < 4; ++mf)
#pragma unroll
            for (int nf = 0; nf < 4; ++nf) {
                f32x4 c = acc[mf][nf];
                c = __builtin_amdgcn_mfma_f32_16x16x32_bf16(al[mf], bh[nf], c, 0, 0, 0);
                c = __builtin_amdgcn_mfma_f32_16x16x32_bf16(ah[mf], bl[nf], c, 0, 0, 0);
                c = __builtin_amdgcn_mfma_f32_16x16x32_bf16(ah[mf], bh[nf], c, 0, 0, 0);
                acc[mf][nf] = c;
            }
    }

    float bv[4];
#pragma unroll
    for (int nf = 0; nf < 4; ++nf) bv[nf] = bsel[ncol0 + nf * 16 + lrow];
#pragma unroll
    for (int mf = 0; mf < 4; ++mf) {
#pragma unroll
        for (int r = 0; r < 4; ++r) {
            const int row = row0 + mf * 16 + kg * 4 + r;
            const int bidx = row / HW_;
            const int hw = row - bidx * HW_;
#pragma unroll
            for (int nf = 0; nf < 4; ++nf) {
                const int c = ncol0 + nf * 16 + lrow;
                obase[((size_t)(bidx * 256 + c)) * HW_ + hw] = acc[mf][nf][r] + bv[nf];
            }
        }
    }
}

// ---------------------------------------------------------------------------
// 22x22 blocked mean pool of cat([xcl, xel]) -> pooled (B,36,512)  (unchanged)
// ---------------------------------------------------------------------------
__global__ __launch_bounds__(256)
void pool_k(const float* __restrict__ xcl, const float* __restrict__ xel,
            float* __restrict__ pooled) {
    const int q = blockIdx.x;   // 0..35
    const int b = blockIdx.y;
    const int wi = q / 6, wj = q % 6;
    const int tid = threadIdx.x;
    const size_t base = ((size_t)(b * HW_ + wi * 22 * WID + wj * 22)) * CH + tid;
    const float* p0 = xcl + base;
    const float* p1 = xel + base;
    float s0 = 0.f, s1 = 0.f;
    for (int iy = 0; iy < 22; ++iy) {
        const size_t ro = (size_t)iy * WID * CH;
        for (int ix = 0; ix < 22; ++ix) {
            const size_t off = ro + (size_t)ix * CH;
            s0 += p0[off];
            s1 += p1[off];
        }
    }
    const float inv = 1.0f / 484.0f;
    float* dst = pooled + (size_t)(b * 36 + q) * 512;
    dst[tid] = s0 * inv;
    dst[256 + tid] = s1 * inv;
}

// ---------------------------------------------------------------------------
// m = pooled @ xe_w + xe_b  (rows = 288, K = 512, N = 128)  (unchanged)
// ---------------------------------------------------------------------------
__global__ __launch_bounds__(128)
void mproj_k(const float* __restrict__ pooled, const float* __restrict__ xe_w,
             const float* __restrict__ xe_b, float* __restrict__ mbuf) {
    __shared__ float p[512];
    const int q = blockIdx.x, b = blockIdx.y, tid = threadIdx.x;
    const float* prow = pooled + (size_t)(b * 36 + q) * 512;
    for (int i = tid; i < 512; i += 128) p[i] = prow[i];
    __syncthreads();
    float acc = xe_b[tid];
    for (int k = 0; k < 512; ++k) acc += p[k] * xe_w[k * 128 + tid];
    mbuf[(size_t)(b * 36 + q) * 128 + tid] = acc;
}

// ---------------------------------------------------------------------------
// Attention: one block per (b, head, q). Online softmax over HW_ keys. (unchanged)
// ---------------------------------------------------------------------------
__global__ __launch_bounds__(256)
void attn_k(const float* __restrict__ mbuf, const float* __restrict__ kv,
            float* __restrict__ aout) {
    const int q = blockIdx.x, head = blockIdx.y, b = blockIdx.z;
    const int tid = threadIdx.x;
    const float* mv = mbuf + (size_t)(b * 36 + q) * 128 + head * 16;
    float4 m0 = *(const float4*)(mv + 0);
    float4 m1 = *(const float4*)(mv + 4);
    float4 m2 = *(const float4*)(mv + 8);
    float4 m3 = *(const float4*)(mv + 12);
    float mx = -INFINITY, sum = 0.f;
    float4 a0 = {0, 0, 0, 0}, a1 = {0, 0, 0, 0}, a2 = {0, 0, 0, 0}, a3 = {0, 0, 0, 0};
    for (int j = tid; j < HW_; j += 256) {
        const float* row = kv + ((size_t)(b * HW_ + j)) * 256 + head * 16;
        float4 k0 = *(const float4*)(row + 0);
        float4 k1 = *(const float4*)(row + 4);
        float4 k2 = *(const float4*)(row + 8);
        float4 k3 = *(const float4*)(row + 12);
        float s = m0.x * k0.x + m0.y * k0.y + m0.z * k0.z + m0.w * k0.w
                + m1.x * k1.x + m1.y * k1.y + m1.z * k1.z + m1.w * k1.w
                + m2.x * k2.x + m2.y * k2.y + m2.z * k2.z + m2.w * k2.w
                + m3.x * k3.x + m3.y * k3.y + m3.z * k3.z + m3.w * k3.w;
        s *= 0.25f;
        const float nm = fmaxf(mx, s);
        const float corr = expf(mx - nm);
        const float p = expf(s - nm);
        sum = sum * corr + p;
        const float* vr = row + 128;
        float4 v0 = *(const float4*)(vr + 0);
        float4 v1 = *(const float4*)(vr + 4);
        float4 v2 = *(const float4*)(vr + 8);
        float4 v3 = *(const float4*)(vr + 12);
        a0.x = a0.x * corr + p * v0.x; a0.y = a0.y * corr + p * v0.y;
        a0.z = a0.z * corr + p * v0.z; a0.w = a0.w * corr + p * v0.w;
        a1.x = a1.x * corr + p * v1.x; a1.y = a1.y * corr + p * v1.y;
        a1.z = a1.z * corr + p * v1.z; a1.w = a1.w * corr + p * v1.w;
        a2.x = a2.x * corr + p * v2.x; a2.y = a2.y * corr + p * v2.y;
        a2.z = a2.z * corr + p * v2.z; a2.w = a2.w * corr + p * v2.w;
        a3.x = a3.x * corr + p * v3.x; a3.y = a3.y * corr + p * v3.y;
        a3.z = a3.z * corr + p * v3.z; a3.w = a3.w * corr + p * v3.w;
        mx = nm;
    }
    __shared__ float smax[256];
    __shared__ float ssum[256];
    __shared__ float sacc[256][16];
    smax[tid] = mx; ssum[tid] = sum;
    float* sa = sacc[tid];
    sa[0] = a0.x; sa[1] = a0.y; sa[2] = a0.z; sa[3] = a0.w;
    sa[4] = a1.x; sa[5] = a1.y; sa[6] = a1.z; sa[7] = a1.w;
    sa[8] = a2.x; sa[9] = a2.y; sa[10] = a2.z; sa[11] = a2.w;
    sa[12] = a3.x; sa[13] = a3.y; sa[14] = a3.z; sa[15] = a3.w;
    for (int off = 128; off > 0; off >>= 1) {
        __syncthreads();
        if (tid < off) {
            const float ma = smax[tid], mb = smax[tid + off];
            const float nm = fmaxf(ma, mb);
            const float ea = expf(ma - nm), eb = expf(mb - nm);
            ssum[tid] = ssum[tid] * ea + ssum[tid + off] * eb;
            for (int i = 0; i < 16; ++i)
                sacc[tid][i] = sacc[tid][i] * ea + sacc[tid + off][i] * eb;
            smax[tid] = nm;
        }
    }
    __syncthreads();
    if (tid < 16)
        aout[((size_t)(b * 8 + head) * 36 + q) * 16 + tid] = sacc[0][tid] / ssum[0];
}

// ---------------------------------------------------------------------------
// Bilinear upsample 6x6 -> 132x132  (unchanged)
// ---------------------------------------------------------------------------
__global__ __launch_bounds__(256)
void upsample_k(const float* __restrict__ aout, float* __restrict__ g) {
    const int tid = threadIdx.x;
    const int c = tid & 127;
    const int hw = blockIdx.x * 2 + (tid >> 7);
    const int b = blockIdx.y;
    const int h = hw / WID;
    const int w = hw - h * WID;
    const float fy = (h - 10.5f) * (1.0f / 22.0f);
    const float fx = (w - 10.5f) * (1.0f / 22.0f);
    float y0f = floorf(fy), x0f = floorf(fx);
    const float ty = fy - y0f, tx = fx - x0f;
    int y0 = (int)y0f, x0 = (int)x0f;
    int y1 = min(y0 + 1, 5), x1 = min(x0 + 1, 5);
    y0 = max(y0, 0); x0 = max(x0, 0);
    const int head = c >> 4, di = c & 15;
    const float* src = aout + ((size_t)(b * 8 + head) * 36) * 16 + di;
    const float s00 = src[(y0 * 6 + x0) * 16];
    const float s01 = src[(y0 * 6 + x1) * 16];
    const float s10 = src[(y1 * 6 + x0) * 16];
    const float s11 = src[(y1 * 6 + x1) * 16];
    const float v = (1.f - ty) * ((1.f - tx) * s00 + tx * s01)
                  + ty * ((1.f - tx) * s10 + tx * s11);
    g[((size_t)(b * HW_ + hw)) * 128 + c] = v;
}

// ---------------------------------------------------------------------------
// Depthwise 7x7 conv, pad 3, channels-last (M,128), + bias  (unchanged)
// ---------------------------------------------------------------------------
__global__ __launch_bounds__(256)
void dwconv_k(const float* __restrict__ in, const float* __restrict__ cw,
              const float* __restrict__ cb, float* __restrict__ out) {
    __shared__ float wl[128 * 49];
    const int tid = threadIdx.x;
    for (int i = tid; i < 128 * 49; i += 256) wl[i] = cw[i];
    __syncthreads();
    const int c = tid & 127;
    const int w = blockIdx.x * 2 + (tid >> 7);
    const int h = blockIdx.y;
    const int b = blockIdx.z;
    const float* ib = in + ((size_t)b * HW_) * 128 + c;
    const float* wc = &wl[c * 49];
    float acc = cb[c];
    for (int ky = 0; ky < 7; ++ky) {
        const int y = h + ky - 3;
        if ((unsigned)y >= (unsigned)HGT) continue;
        const size_t ro = (size_t)y * WID * 128;
        for (int kx = 0; kx < 7; ++kx) {
            const int x = w + kx - 3;
            if ((unsigned)x >= (unsigned)WID) continue;
            acc += ib[ro + (size_t)x * 128] * wc[ky * 7 + kx];
        }
    }
    out[((size_t)(b * HW_ + h * WID + w)) * 128 + c] = acc;
}

// ---------------------------------------------------------------------------
extern "C" void kernel_launch(void* const* d_in, const int* in_sizes, int n_in,
                              void* d_out, int out_size, void* d_ws, size_t ws_size,
                              hipStream_t stream) {
    const float* x      = (const float*)d_in[0];
    const float* x_e    = (const float*)d_in[1];
    const float* norm_w = (const float*)d_in[2];
    const float* norm_b = (const float*)d_in[3];
    const float* norme_w= (const float*)d_in[4];
    const float* norme_b= (const float*)d_in[5];
    const float* l_w    = (const float*)d_in[6];
    const float* l_b    = (const float*)d_in[7];
    const float* kv_w   = (const float*)d_in[8];
    const float* kv_b   = (const float*)d_in[9];
    const float* xe_w   = (const float*)d_in[10];
    const float* xe_b   = (const float*)d_in[11];
    const float* q_w    = (const float*)d_in[12];
    const float* q_b    = (const float*)d_in[13];
    const float* ef_w   = (const float*)d_in[14];
    const float* ef_b   = (const float*)d_in[15];
    const float* ec_w   = (const float*)d_in[16];
    const float* ec_b   = (const float*)d_in[17];
    const float* eb_w   = (const float*)d_in[18];
    const float* eb_b   = (const float*)d_in[19];
    const float* proj_w = (const float*)d_in[20];
    const float* proj_b = (const float*)d_in[21];
    const float* proje_w= (const float*)d_in[22];
    const float* proje_b= (const float*)d_in[23];
    float* out = (float*)d_out;

    float* ws = (float*)d_ws;
    const size_t MS = (size_t)MROWS * 256;
    const size_t MH = (size_t)MROWS * 128;
    float* P0 = ws;                // xcl  (M,256)
    float* P1 = ws + MS;           // xel  (M,256)
    float* P2 = ws + 2 * MS;       // xg ; later P2a=ef/g, P2b=conv
    float* P3 = ws + 3 * MS;       // kv ; later P3a=l1, P3b=l2
    float* pooled = ws + 4 * MS;
    float* mbuf = pooled + 147456;
    float* aout = mbuf + 36864;
    float* P2a = P2;
    float* P2b = P2 + MH;
    float* P3a = P3;
    float* P3b = P3 + MH;

    const dim3 blk(256);
    // 1. LayerNorms (transpose to channels-last)
    ln_k<<<dim3(HW_ / 4, 8), blk, 0, stream>>>(x, norm_w, norm_b, P0);
    ln_k<<<dim3(HW_ / 4, 8), blk, 0, stream>>>(x_e, norme_w, norme_b, P1);
    // 2. xg = gelu(xcl @ l_w + l_b)
    mgemm_k<1, 256, 256><<<dim3(2, MROWS / 128), blk, 0, stream>>>(P0, l_w, l_b, P2, nullptr);
    // 3. kv = xg @ kv_w + kv_b
    mgemm_k<0, 256, 256><<<dim3(2, MROWS / 128), blk, 0, stream>>>(P2, kv_w, kv_b, P3, nullptr);
    // 4. pooled 6x6 of cat
    pool_k<<<dim3(36, 8), blk, 0, stream>>>(P0, P1, pooled);
    // 5. m projection
    mproj_k<<<dim3(36, 8), dim3(128), 0, stream>>>(pooled, xe_w, xe_b, mbuf);
    // 6. attention -> aout (B,8,36,16)
    attn_k<<<dim3(36, 8, 8), blk, 0, stream>>>(mbuf, P3, aout);
    // 7. LFA1: ef1 -> P2a ; conv -> P2b ; q1 -> P3a ; l1 = e*q -> P3a
    mgemm_k<0, 256, 128><<<dim3(1, MROWS / 128), blk, 0, stream>>>(P1, ef_w, ef_b, P2a, nullptr);
    dwconv_k<<<dim3(WID / 2, HGT, 8), blk, 0, stream>>>(P2a, ec_w, ec_b, P2b);
    mgemm_k<0, 256, 128><<<dim3(1, MROWS / 128), blk, 0, stream>>>(P0, q_w, q_b, P3a, nullptr);
    mgemm_k<2, 128, 128><<<dim3(1, MROWS / 128), blk, 0, stream>>>(P2b, eb_w, eb_b, P3a, P3a);
    // 8. LFA2 (swapped inputs) -> P3b
    mgemm_k<0, 256, 128><<<dim3(1, MROWS / 128), blk, 0, stream>>>(P0, ef_w, ef_b, P2a, nullptr);
    dwconv_k<<<dim3(WID / 2, HGT, 8), blk, 0, stream>>>(P2a, ec_w, ec_b, P2b);
    mgemm_k<0, 256, 128><<<dim3(1, MROWS / 128), blk, 0, stream>>>(P1, q_w, q_b, P3b, nullptr);
    mgemm_k<2, 128, 128><<<dim3(1, MROWS / 128), blk, 0, stream>>>(P2b, eb_w, eb_b, P3b, P3b);
    // 9. g = upsample(attention out) -> P2a
    upsample_k<<<dim3(HW_ / 2, 8), blk, 0, stream>>>(aout, P2a);
    // 10. fused final projection -> d_out (out, out_e)
    mgemm_proj_k<<<dim3(4, MROWS / 128), blk, 0, stream>>>(
        P2a, P3a, P3b, proj_w, proj_b, proje_w, proje_b, out);
}

// Round 2
// 2488.380 us; speedup vs baseline: 1.6447x; 1.6447x over previous
//
#include <hip/hip_runtime.h>
#include <math.h>

#define HW_ 17424
#define WID 132
#define HGT 132
#define CH 256
#define MROWS 139392          // 8*17424
#define OUTOFF 35684352       // 8*256*17424

typedef __bf16 bf16x8 __attribute__((ext_vector_type(8)));
typedef float  f32x4  __attribute__((ext_vector_type(4)));

// Split 8 fp32 into hi/lo bf16 (RNE; residual is exact in fp32).
__device__ __forceinline__ void split8(const float* v, bf16x8& hi, bf16x8& lo) {
#pragma unroll
    for (int e = 0; e < 8; ++e) {
        float f = v[e];
        __bf16 h = (__bf16)f;
        hi[e] = h;
        lo[e] = (__bf16)(f - (float)h);
    }
}

// ---------------------------------------------------------------------------
// LayerNorm over channels with BCHW -> (M,256) transpose.  (unchanged, verified)
// ---------------------------------------------------------------------------
__global__ __launch_bounds__(256)
void ln_k(const float* __restrict__ x, const float* __restrict__ w,
          const float* __restrict__ bias, float* __restrict__ out) {
    __shared__ float4 s1[256];
    __shared__ float4 s2[256];
    const int tid = threadIdx.x;              // channel
    const int b   = blockIdx.y;
    const int hw0 = blockIdx.x << 2;          // 4 positions
    const float* px = x + ((size_t)(b * CH + tid)) * HW_ + hw0;
    float4 v = *(const float4*)px;
    s1[tid] = v;
    s2[tid] = make_float4(v.x * v.x, v.y * v.y, v.z * v.z, v.w * v.w);
    __syncthreads();
    for (int off = 128; off > 0; off >>= 1) {
        if (tid < off) {
            float4 a = s1[tid], c = s1[tid + off];
            a.x += c.x; a.y += c.y; a.z += c.z; a.w += c.w;
            s1[tid] = a;
            float4 d = s2[tid], e = s2[tid + off];
            d.x += e.x; d.y += e.y; d.z += e.z; d.w += e.w;
            s2[tid] = d;
        }
        __syncthreads();
    }
    float4 sum = s1[0], sq = s2[0];
    const float wv = w[tid], bv = bias[tid];
    const float inv = 1.0f / 256.0f;
    float o[4];
    {
        float m = sum.x * inv; float var = sq.x * inv - m * m;
        o[0] = (v.x - m) * rsqrtf(var + 1e-6f) * wv + bv;
    }
    {
        float m = sum.y * inv; float var = sq.y * inv - m * m;
        o[1] = (v.y - m) * rsqrtf(var + 1e-6f) * wv + bv;
    }
    {
        float m = sum.z * inv; float var = sq.z * inv - m * m;
        o[2] = (v.z - m) * rsqrtf(var + 1e-6f) * wv + bv;
    }
    {
        float m = sum.w * inv; float var = sq.w * inv - m * m;
        o[3] = (v.w - m) * rsqrtf(var + 1e-6f) * wv + bv;
    }
    float* po = out + ((size_t)(b * HW_ + hw0)) * CH + tid;
    po[0] = o[0]; po[256] = o[1]; po[512] = o[2]; po[768] = o[3];
}

// ---------------------------------------------------------------------------
// bf16x3 split-precision MFMA GEMM  (unchanged, verified round 1)
// ---------------------------------------------------------------------------
template <int EPI, int KK, int NN>
__global__ __launch_bounds__(256, 2)
void mgemm_k(const float* __restrict__ A, const float* __restrict__ W,
             const float* __restrict__ bias, float* __restrict__ C,
             const float* __restrict__ mulbuf) {
    const int tid  = threadIdx.x;
    const int lane = tid & 63;
    const int wave = tid >> 6;
    const int wm = wave >> 1, wn = wave & 1;
    const int row0 = blockIdx.y * 128 + wm * 64;
    const int col0 = blockIdx.x * 128 + wn * 64;
    const int lrow = lane & 15;
    const int kg   = lane >> 4;

    const f32x4 zero = {0.f, 0.f, 0.f, 0.f};
    f32x4 acc[4][4];
#pragma unroll
    for (int i = 0; i < 4; ++i)
#pragma unroll
        for (int j = 0; j < 4; ++j) acc[i][j] = zero;

    for (int kt = 0; kt < KK; kt += 32) {
        const int kb = kt + kg * 8;
        bf16x8 ah[4], al[4], bh[4], bl[4];
#pragma unroll
        for (int mf = 0; mf < 4; ++mf) {
            const float* p = A + (size_t)(row0 + mf * 16 + lrow) * KK + kb;
            float buf[8];
            *(float4*)&buf[0] = *(const float4*)p;
            *(float4*)&buf[4] = *(const float4*)(p + 4);
            split8(buf, ah[mf], al[mf]);
        }
#pragma unroll
        for (int nf = 0; nf < 4; ++nf) {
            const float* p = W + (size_t)kb * NN + col0 + nf * 16 + lrow;
            float buf[8];
#pragma unroll
            for (int e = 0; e < 8; ++e) buf[e] = p[(size_t)e * NN];
            split8(buf, bh[nf], bl[nf]);
        }
#pragma unroll
        for (int mf = 0; mf < 4; ++mf)
#pragma unroll
            for (int nf = 0; nf < 4; ++nf) {
                f32x4 c = acc[mf][nf];
                c = __builtin_amdgcn_mfma_f32_16x16x32_bf16(al[mf], bh[nf], c, 0, 0, 0);
                c = __builtin_amdgcn_mfma_f32_16x16x32_bf16(ah[mf], bl[nf], c, 0, 0, 0);
                c = __builtin_amdgcn_mfma_f32_16x16x32_bf16(ah[mf], bh[nf], c, 0, 0, 0);
                acc[mf][nf] = c;
            }
    }

    float bv[4];
#pragma unroll
    for (int nf = 0; nf < 4; ++nf) bv[nf] = bias[col0 + nf * 16 + lrow];
#pragma unroll
    for (int mf = 0; mf < 4; ++mf) {
#pragma unroll
        for (int r = 0; r < 4; ++r) {
            const int row = row0 + mf * 16 + kg * 4 + r;
#pragma unroll
            for (int nf = 0; nf < 4; ++nf) {
                const int col = col0 + nf * 16 + lrow;
                const size_t off = (size_t)row * NN + col;
                float v = acc[mf][nf][r] + bv[nf];
                if (EPI == 1) v = 0.5f * v * (1.0f + erff(v * 0.7071067811865475f));
                if (EPI == 2) v *= mulbuf[off];
                C[off] = v;
            }
        }
    }
}

// ---------------------------------------------------------------------------
// Final projection, bf16x3 MFMA  (unchanged, verified round 1)
// ---------------------------------------------------------------------------
__global__ __launch_bounds__(256, 2)
void mgemm_proj_k(const float* __restrict__ g, const float* __restrict__ l1,
                  const float* __restrict__ l2,
                  const float* __restrict__ w1, const float* __restrict__ b1,
                  const float* __restrict__ w2, const float* __restrict__ b2,
                  float* __restrict__ out) {
    const int tid  = threadIdx.x;
    const int lane = tid & 63;
    const int wave = tid >> 6;
    const int wm = wave >> 1, wn = wave & 1;
    const int row0  = blockIdx.y * 128 + wm * 64;
    const int half  = blockIdx.x >> 1;              // 0 -> proj, 1 -> proje
    const int ncol0 = (blockIdx.x & 1) * 128 + wn * 64;
    const float* Wsel = half ? w2 : w1;
    const float* bsel = half ? b2 : b1;
    float* obase = out + (half ? (size_t)OUTOFF : (size_t)0);
    const int lrow = lane & 15;
    const int kg   = lane >> 4;

    const f32x4 zero = {0.f, 0.f, 0.f, 0.f};
    f32x4 acc[4][4];
#pragma unroll
    for (int i = 0; i < 4; ++i)
#pragma unroll
        for (int j = 0; j < 4; ++j) acc[i][j] = zero;

    for (int kt = 0; kt < 384; kt += 32) {
        const float* Ab = (kt < 128) ? g : (kt < 256) ? l1 : l2;
        const int kloc = (kt & 127) + kg * 8;
        bf16x8 ah[4], al[4], bh[4], bl[4];
#pragma unroll
        for (int mf = 0; mf < 4; ++mf) {
            const float* p = Ab + (size_t)(row0 + mf * 16 + lrow) * 128 + kloc;
            float buf[8];
            *(float4*)&buf[0] = *(const float4*)p;
            *(float4*)&buf[4] = *(const float4*)(p + 4);
            split8(buf, ah[mf], al[mf]);
        }
#pragma unroll
        for (int nf = 0; nf < 4; ++nf) {
            const float* p = Wsel + (size_t)(kt + kg * 8) * 256 + ncol0 + nf * 16 + lrow;
            float buf[8];
#pragma unroll
            for (int e = 0; e < 8; ++e) buf[e] = p[(size_t)e * 256];
            split8(buf, bh[nf], bl[nf]);
        }
#pragma unroll
        for (int mf = 0; mf < 4; ++mf)
#pragma unroll
            for (int nf = 0; nf < 4; ++nf) {
                f32x4 c = acc[mf][nf];
                c = __builtin_amdgcn_mfma_f32_16x16x32_bf16(al[mf], bh[nf], c, 0, 0, 0);
                c = __builtin_amdgcn_mfma_f32_16x16x32_bf16(ah[mf], bl[nf], c, 0, 0, 0);
                c = __builtin_amdgcn_mfma_f32_16x16x32_bf16(ah[mf], bh[nf], c, 0, 0, 0);
                acc[mf][nf] = c;
            }
    }

    float bv[4];
#pragma unroll
    for (int nf = 0; nf < 4; ++nf) bv[nf] = bsel[ncol0 + nf * 16 + lrow];
#pragma unroll
    for (int mf = 0; mf < 4; ++mf) {
#pragma unroll
        for (int r = 0; r < 4; ++r) {
            const int row = row0 + mf * 16 + kg * 4 + r;
            const int bidx = row / HW_;
            const int hw = row - bidx * HW_;
#pragma unroll
            for (int nf = 0; nf < 4; ++nf) {
                const int c = ncol0 + nf * 16 + lrow;
                obase[((size_t)(bidx * 256 + c)) * HW_ + hw] = acc[mf][nf][r] + bv[nf];
            }
        }
    }
}

// ---------------------------------------------------------------------------
// 22x22 blocked mean pool  (unchanged)
// ---------------------------------------------------------------------------
__global__ __launch_bounds__(256)
void pool_k(const float* __restrict__ xcl, const float* __restrict__ xel,
            float* __restrict__ pooled) {
    const int q = blockIdx.x;   // 0..35
    const int b = blockIdx.y;
    const int wi = q / 6, wj = q % 6;
    const int tid = threadIdx.x;
    const size_t base = ((size_t)(b * HW_ + wi * 22 * WID + wj * 22)) * CH + tid;
    const float* p0 = xcl + base;
    const float* p1 = xel + base;
    float s0 = 0.f, s1 = 0.f;
    for (int iy = 0; iy < 22; ++iy) {
        const size_t ro = (size_t)iy * WID * CH;
        for (int ix = 0; ix < 22; ++ix) {
            const size_t off = ro + (size_t)ix * CH;
            s0 += p0[off];
            s1 += p1[off];
        }
    }
    const float inv = 1.0f / 484.0f;
    float* dst = pooled + (size_t)(b * 36 + q) * 512;
    dst[tid] = s0 * inv;
    dst[256 + tid] = s1 * inv;
}

// ---------------------------------------------------------------------------
// m = pooled @ xe_w + xe_b  (unchanged)
// ---------------------------------------------------------------------------
__global__ __launch_bounds__(128)
void mproj_k(const float* __restrict__ pooled, const float* __restrict__ xe_w,
             const float* __restrict__ xe_b, float* __restrict__ mbuf) {
    __shared__ float p[512];
    const int q = blockIdx.x, b = blockIdx.y, tid = threadIdx.x;
    const float* prow = pooled + (size_t)(b * 36 + q) * 512;
    for (int i = tid; i < 512; i += 128) p[i] = prow[i];
    __syncthreads();
    float acc = xe_b[tid];
    for (int k = 0; k < 512; ++k) acc += p[k] * xe_w[k * 128 + tid];
    mbuf[(size_t)(b * 36 + q) * 128 + tid] = acc;
}

// ---------------------------------------------------------------------------
// Attention: one block per (b, head, group of 6 q). Online softmax over HW_
// keys; kv streamed ONCE per block (6x less kv traffic than 1-q-per-block).
// Same online-softmax recurrence and merge tree as the verified version.
// ---------------------------------------------------------------------------
__global__ __launch_bounds__(256)
void attn_k(const float* __restrict__ mbuf, const float* __restrict__ kv,
            float* __restrict__ aout) {
    const int qg = blockIdx.x;          // 0..5 (6 queries each)
    const int head = blockIdx.y, b = blockIdx.z;
    const int tid = threadIdx.x;
    __shared__ float ml[6][16];
    if (tid < 96) {
        const int q = tid >> 4, d = tid & 15;
        ml[q][d] = mbuf[(size_t)(b * 36 + qg * 6 + q) * 128 + head * 16 + d];
    }
    __syncthreads();

    float mx[6], sum[6], a[6][16];
#pragma unroll
    for (int q = 0; q < 6; ++q) {
        mx[q] = -INFINITY; sum[q] = 0.f;
#pragma unroll
        for (int d = 0; d < 16; ++d) a[q][d] = 0.f;
    }

    for (int j = tid; j < HW_; j += 256) {
        const float* row = kv + ((size_t)(b * HW_ + j)) * 256 + head * 16;
        float k[16], v[16];
        *(float4*)&k[0]  = *(const float4*)(row + 0);
        *(float4*)&k[4]  = *(const float4*)(row + 4);
        *(float4*)&k[8]  = *(const float4*)(row + 8);
        *(float4*)&k[12] = *(const float4*)(row + 12);
        const float* vr = row + 128;
        *(float4*)&v[0]  = *(const float4*)(vr + 0);
        *(float4*)&v[4]  = *(const float4*)(vr + 4);
        *(float4*)&v[8]  = *(const float4*)(vr + 8);
        *(float4*)&v[12] = *(const float4*)(vr + 12);
#pragma unroll
        for (int q = 0; q < 6; ++q) {
            float s = 0.f;
#pragma unroll
            for (int d = 0; d < 16; ++d) s += ml[q][d] * k[d];
            s *= 0.25f;    // d^-0.5, d=16
            const float nm = fmaxf(mx[q], s);
            const float corr = expf(mx[q] - nm);
            const float p = expf(s - nm);
            sum[q] = sum[q] * corr + p;
#pragma unroll
            for (int d = 0; d < 16; ++d) a[q][d] = a[q][d] * corr + p * v[d];
            mx[q] = nm;
        }
    }

    __shared__ float smax[256];
    __shared__ float ssum[256];
    __shared__ float sacc[256][16];
    for (int q = 0; q < 6; ++q) {
        __syncthreads();
        smax[tid] = mx[q]; ssum[tid] = sum[q];
#pragma unroll
        for (int d = 0; d < 16; ++d) sacc[tid][d] = a[q][d];
        for (int off = 128; off > 0; off >>= 1) {
            __syncthreads();
            if (tid < off) {
                const float ma = smax[tid], mb = smax[tid + off];
                const float nm = fmaxf(ma, mb);
                const float ea = expf(ma - nm), eb = expf(mb - nm);
                ssum[tid] = ssum[tid] * ea + ssum[tid + off] * eb;
                for (int d = 0; d < 16; ++d)
                    sacc[tid][d] = sacc[tid][d] * ea + sacc[tid + off][d] * eb;
                smax[tid] = nm;
            }
        }
        __syncthreads();
        if (tid < 16)
            aout[((size_t)(b * 8 + head) * 36 + qg * 6 + q) * 16 + tid] =
                sacc[0][tid] / ssum[0];
    }
}

// ---------------------------------------------------------------------------
// Bilinear upsample 6x6 -> 132x132  (unchanged)
// ---------------------------------------------------------------------------
__global__ __launch_bounds__(256)
void upsample_k(const float* __restrict__ aout, float* __restrict__ g) {
    const int tid = threadIdx.x;
    const int c = tid & 127;
    const int hw = blockIdx.x * 2 + (tid >> 7);
    const int b = blockIdx.y;
    const int h = hw / WID;
    const int w = hw - h * WID;
    const float fy = (h - 10.5f) * (1.0f / 22.0f);
    const float fx = (w - 10.5f) * (1.0f / 22.0f);
    float y0f = floorf(fy), x0f = floorf(fx);
    const float ty = fy - y0f, tx = fx - x0f;
    int y0 = (int)y0f, x0 = (int)x0f;
    int y1 = min(y0 + 1, 5), x1 = min(x0 + 1, 5);
    y0 = max(y0, 0); x0 = max(x0, 0);
    const int head = c >> 4, di = c & 15;
    const float* src = aout + ((size_t)(b * 8 + head) * 36) * 16 + di;
    const float s00 = src[(y0 * 6 + x0) * 16];
    const float s01 = src[(y0 * 6 + x1) * 16];
    const float s10 = src[(y1 * 6 + x0) * 16];
    const float s11 = src[(y1 * 6 + x1) * 16];
    const float v = (1.f - ty) * ((1.f - tx) * s00 + tx * s01)
                  + ty * ((1.f - tx) * s10 + tx * s11);
    g[((size_t)(b * HW_ + hw)) * 128 + c] = v;
}

// ---------------------------------------------------------------------------
// Depthwise 7x7 conv, pad 3, channels-last (M,128), + bias.
// Sliding-window rewrite: thread = (channel, 22-wide x-strip of one row).
// Per ky-row, load the 28-value window ONCE and reuse across 7 taps x 22
// outputs: 8.9 loads/output vs 49 in the naive version (latency-bound fix).
// ---------------------------------------------------------------------------
__global__ __launch_bounds__(256)
void dwconv_k(const float* __restrict__ in, const float* __restrict__ cw,
              const float* __restrict__ cb, float* __restrict__ out) {
    __shared__ float wl[128 * 49];
    const int tid = threadIdx.x;
    for (int i = tid; i < 128 * 49; i += 256) wl[i] = cw[i];
    __syncthreads();
    const int c  = tid & 127;
    const int xb = ((blockIdx.x << 1) + (tid >> 7)) * 22;   // 0,22,...,110
    const int h  = blockIdx.y;
    const int b  = blockIdx.z;
    const float* wc = &wl[c * 49];
    float acc[22];
    const float bias = cb[c];
#pragma unroll
    for (int i = 0; i < 22; ++i) acc[i] = bias;
    const float* ibase = in + ((size_t)b * HW_) * 128 + c;
    for (int ky = 0; ky < 7; ++ky) {
        const int y = h + ky - 3;
        if ((unsigned)y >= (unsigned)HGT) continue;
        const float* rp = ibase + (size_t)y * WID * 128;
        float v[28];
#pragma unroll
        for (int j = 0; j < 28; ++j) {
            const int x = xb - 3 + j;
            v[j] = ((unsigned)x < (unsigned)WID) ? rp[(size_t)x * 128] : 0.f;
        }
#pragma unroll
        for (int kx = 0; kx < 7; ++kx) {
            const float wv = wc[ky * 7 + kx];
#pragma unroll
            for (int i = 0; i < 22; ++i) acc[i] += v[i + kx] * wv;
        }
    }
    float* op = out + ((size_t)(b * HW_ + h * WID + xb)) * 128 + c;
#pragma unroll
    for (int i = 0; i < 22; ++i) op[(size_t)i * 128] = acc[i];
}

// ---------------------------------------------------------------------------
extern "C" void kernel_launch(void* const* d_in, const int* in_sizes, int n_in,
                              void* d_out, int out_size, void* d_ws, size_t ws_size,
                              hipStream_t stream) {
    const float* x      = (const float*)d_in[0];
    const float* x_e    = (const float*)d_in[1];
    const float* norm_w = (const float*)d_in[2];
    const float* norm_b = (const float*)d_in[3];
    const float* norme_w= (const float*)d_in[4];
    const float* norme_b= (const float*)d_in[5];
    const float* l_w    = (const float*)d_in[6];
    const float* l_b    = (const float*)d_in[7];
    const float* kv_w   = (const float*)d_in[8];
    const float* kv_b   = (const float*)d_in[9];
    const float* xe_w   = (const float*)d_in[10];
    const float* xe_b   = (const float*)d_in[11];
    const float* q_w    = (const float*)d_in[12];
    const float* q_b    = (const float*)d_in[13];
    const float* ef_w   = (const float*)d_in[14];
    const float* ef_b   = (const float*)d_in[15];
    const float* ec_w   = (const float*)d_in[16];
    const float* ec_b   = (const float*)d_in[17];
    const float* eb_w   = (const float*)d_in[18];
    const float* eb_b   = (const float*)d_in[19];
    const float* proj_w = (const float*)d_in[20];
    const float* proj_b = (const float*)d_in[21];
    const float* proje_w= (const float*)d_in[22];
    const float* proje_b= (const float*)d_in[23];
    float* out = (float*)d_out;

    float* ws = (float*)d_ws;
    const size_t MS = (size_t)MROWS * 256;
    const size_t MH = (size_t)MROWS * 128;
    float* P0 = ws;                // xcl  (M,256)
    float* P1 = ws + MS;           // xel  (M,256)
    float* P2 = ws + 2 * MS;       // xg ; later P2a=ef/g, P2b=conv
    float* P3 = ws + 3 * MS;       // kv ; later P3a=l1, P3b=l2
    float* pooled = ws + 4 * MS;
    float* mbuf = pooled + 147456;
    float* aout = mbuf + 36864;
    float* P2a = P2;
    float* P2b = P2 + MH;
    float* P3a = P3;
    float* P3b = P3 + MH;

    const dim3 blk(256);
    // 1. LayerNorms (transpose to channels-last)
    ln_k<<<dim3(HW_ / 4, 8), blk, 0, stream>>>(x, norm_w, norm_b, P0);
    ln_k<<<dim3(HW_ / 4, 8), blk, 0, stream>>>(x_e, norme_w, norme_b, P1);
    // 2. xg = gelu(xcl @ l_w + l_b)
    mgemm_k<1, 256, 256><<<dim3(2, MROWS / 128), blk, 0, stream>>>(P0, l_w, l_b, P2, nullptr);
    // 3. kv = xg @ kv_w + kv_b
    mgemm_k<0, 256, 256><<<dim3(2, MROWS / 128), blk, 0, stream>>>(P2, kv_w, kv_b, P3, nullptr);
    // 4. pooled 6x6 of cat
    pool_k<<<dim3(36, 8), blk, 0, stream>>>(P0, P1, pooled);
    // 5. m projection
    mproj_k<<<dim3(36, 8), dim3(128), 0, stream>>>(pooled, xe_w, xe_b, mbuf);
    // 6. attention -> aout (B,8,36,16): 6 queries per block
    attn_k<<<dim3(6, 8, 8), blk, 0, stream>>>(mbuf, P3, aout);
    // 7. LFA1: ef1 -> P2a ; conv -> P2b ; q1 -> P3a ; l1 = e*q -> P3a
    mgemm_k<0, 256, 128><<<dim3(1, MROWS / 128), blk, 0, stream>>>(P1, ef_w, ef_b, P2a, nullptr);
    dwconv_k<<<dim3(3, HGT, 8), blk, 0, stream>>>(P2a, ec_w, ec_b, P2b);
    mgemm_k<0, 256, 128><<<dim3(1, MROWS / 128), blk, 0, stream>>>(P0, q_w, q_b, P3a, nullptr);
    mgemm_k<2, 128, 128><<<dim3(1, MROWS / 128), blk, 0, stream>>>(P2b, eb_w, eb_b, P3a, P3a);
    // 8. LFA2 (swapped inputs) -> P3b
    mgemm_k<0, 256, 128><<<dim3(1, MROWS / 128), blk, 0, stream>>>(P0, ef_w, ef_b, P2a, nullptr);
    dwconv_k<<<dim3(3, HGT, 8), blk, 0, stream>>>(P2a, ec_w, ec_b, P2b);
    mgemm_k<0, 256, 128><<<dim3(1, MROWS / 128), blk, 0, stream>>>(P1, q_w, q_b, P3b, nullptr);
    mgemm_k<2, 128, 128><<<dim3(1, MROWS / 128), blk, 0, stream>>>(P2b, eb_w, eb_b, P3b, P3b);
    // 9. g = upsample(attention out) -> P2a
    upsample_k<<<dim3(HW_ / 2, 8), blk, 0, stream>>>(aout, P2a);
    // 10. fused final projection -> d_out (out, out_e)
    mgemm_proj_k<<<dim3(4, MROWS / 128), blk, 0, stream>>>(
        P2a, P3a, P3b, proj_w, proj_b, proje_w, proje_b, out);
}